// Round 1
// 292.682 us; speedup vs baseline: 1.0121x; 1.0121x over previous
//
#include <hip/hip_runtime.h>
#include <cstddef>

#define A_ATOMS 96
#define BATCH   128
#define NNODES  12288   // B*A
#define NB      8       // nodes per block (node_k)
#define AS      132     // AsL / workS stride (132%32=4)
#define XS      196     // xinS stride (196%32=4)

typedef float v2f __attribute__((ext_vector_type(2)));

__device__ __forceinline__ float silu_f(float x) {
    float e = __expf(-x);
    return x * __builtin_amdgcn_rcpf(1.0f + e);
}
__device__ __forceinline__ v2f silu2(v2f x) {
    v2f r; r.x = silu_f(x.x); r.y = silu_f(x.y); return r;
}

#define RED64(v) { v += __shfl_xor(v, 1); v += __shfl_xor(v, 2); v += __shfl_xor(v, 4); \
                   v += __shfl_xor(v, 8); v += __shfl_xor(v, 16); v += __shfl_xor(v, 32); }
#define RED8(v)  { v += __shfl_xor(v, 1); v += __shfl_xor(v, 2); v += __shfl_xor(v, 4); }

// ===== fused node kernel v3: wave-private 32-col strips ======================
// Thread map: w = wave (0..3) owns cols [32w,32w+32); lane = ry(node 0..7) x
// cx(col-quad 0..7). Weight loads per wave-instr: 8 unique float4 = 128 B
// contiguous (coalescer dedupes the 8-way ry broadcast) -> each weight matrix
// is streamed exactly ONCE per block (was 4x, once per wave).
__global__ __launch_bounds__(256)
void node_k(const float* __restrict__ vrep, const float* __restrict__ mixW1,
            const float* __restrict__ srep,
            const float* __restrict__ sc1W1, const float* __restrict__ sc1b1,
            const float* __restrict__ sc1W2, const float* __restrict__ sc1b2,
            const float* __restrict__ mixW2,
            const float* __restrict__ sc2W1, const float* __restrict__ sc2b1,
            const float* __restrict__ sc2W2, const float* __restrict__ sc2b2,
            float* __restrict__ l0v, float* __restrict__ l1v) {
    __shared__ float AsL[24 * AS];
    __shared__ float xinS[NB * XS];
    __shared__ float s1s[4][64];
    __shared__ float pwp[NB][2][6];   // mix2 partials: [node][wave-2][d*2+o]

    const int t  = threadIdx.x;
    const int w  = t >> 6;        // HW wave 0..3
    const int ln = t & 63;
    const int cx = ln & 7;        // col quad within strip
    const int ry = ln >> 3;       // node / row-group 0..7
    const int cb = w * 32 + cx * 4;   // output column base 0..124
    const int row0  = blockIdx.x * 24;
    const int node0 = blockIdx.x * NB;

    // ---- stage vrep (24x128) and srep (8x128) into LDS (unchanged) ----------
#pragma unroll
    for (int it = 0; it < 3; it++) {
        const int idx = it * 256 + t;
        const int r   = idx >> 5;
        const int c4  = (idx & 31) * 4;
        *(float4*)&AsL[r * AS + c4] = *(const float4*)(vrep + (size_t)(row0 + r) * 128 + c4);
    }
    {
        const int a  = t >> 5;
        const int c4 = (t & 31) * 4;
        *(float4*)&xinS[a * XS + c4] = *(const float4*)(srep + (size_t)(node0 + a) * 128 + c4);
    }
    __syncthreads();

    // ---- mix1: vmix[node ry][dim 0..2][cols cb..cb+3] -----------------------
    float acc[3][4];
#pragma unroll
    for (int i = 0; i < 3; i++)
#pragma unroll
        for (int j = 0; j < 4; j++) acc[i][j] = 0.0f;

    for (int kc = 0; kc < 128; kc += 8) {
        float a0[8], a1[8], a2[8];
        *(float4*)&a0[0] = *(const float4*)&AsL[(3 * ry + 0) * AS + kc];
        *(float4*)&a0[4] = *(const float4*)&AsL[(3 * ry + 0) * AS + kc + 4];
        *(float4*)&a1[0] = *(const float4*)&AsL[(3 * ry + 1) * AS + kc];
        *(float4*)&a1[4] = *(const float4*)&AsL[(3 * ry + 1) * AS + kc + 4];
        *(float4*)&a2[0] = *(const float4*)&AsL[(3 * ry + 2) * AS + kc];
        *(float4*)&a2[4] = *(const float4*)&AsL[(3 * ry + 2) * AS + kc + 4];
#pragma unroll
        for (int kk = 0; kk < 8; kk++) {
            float b[4];
            *(float4*)b = *(const float4*)(mixW1 + (size_t)(kc + kk) * 128 + cb);
#pragma unroll
            for (int j = 0; j < 4; j++) {
                acc[0][j] += a0[kk] * b[j];
                acc[1][j] += a1[kk] * b[j];
                acc[2][j] += a2[kk] * b[j];
            }
        }
    }
    // norms of vV (cols 0..63 -> waves 0,1); all 3 dims live in this thread
    if (w < 2) {
        float nrm[4];
#pragma unroll
        for (int c = 0; c < 4; c++)
            nrm[c] = sqrtf(acc[0][c] * acc[0][c] + acc[1][c] * acc[1][c]
                         + acc[2][c] * acc[2][c]);
        *(float4*)&xinS[ry * XS + 128 + cb] = *(float4*)nrm;
    }
    __syncthreads();

    // ---- sc1 layer 1: xin(192) @ sc1W1(192x128) -> silu -> workS ------------
    float* workS = AsL;
    {
        float acc3[4];
#pragma unroll
        for (int j = 0; j < 4; j++) acc3[j] = 0.0f;
        for (int kc = 0; kc < 192; kc += 8) {
            float af[8];
            *(float4*)&af[0] = *(const float4*)&xinS[ry * XS + kc];
            *(float4*)&af[4] = *(const float4*)&xinS[ry * XS + kc + 4];
#pragma unroll
            for (int kk = 0; kk < 8; kk++) {
                float b[4];
                *(float4*)b = *(const float4*)(sc1W1 + (size_t)(kc + kk) * 128 + cb);
#pragma unroll
                for (int j = 0; j < 4; j++) acc3[j] += af[kk] * b[j];
            }
        }
        float h[4];
#pragma unroll
        for (int j = 0; j < 4; j++) h[j] = silu_f(acc3[j] + sc1b1[cb + j]);
        __syncthreads();
        *(float4*)&workS[ry * AS + cb] = *(float4*)h;
    }
    __syncthreads();

    // ---- sc1 layer 2: h(128) @ sc1W2(128x128) -------------------------------
    float xg[4];
    {
        float acc4[4];
#pragma unroll
        for (int j = 0; j < 4; j++) acc4[j] = 0.0f;
        for (int kc = 0; kc < 128; kc += 8) {
            float af[8];
            *(float4*)&af[0] = *(const float4*)&workS[ry * AS + kc];
            *(float4*)&af[4] = *(const float4*)&workS[ry * AS + kc + 4];
#pragma unroll
            for (int kk = 0; kk < 8; kk++) {
                float b[4];
                *(float4*)b = *(const float4*)(sc1W2 + (size_t)(kc + kk) * 128 + cb);
#pragma unroll
                for (int j = 0; j < 4; j++) acc4[j] += af[kk] * b[j];
            }
        }
        if (w < 2) {               // cols 0..63 = s_out -> xinS (raw; silu in sc2)
            float xs[4];
#pragma unroll
            for (int j = 0; j < 4; j++) xs[j] = acc4[j] + sc1b2[cb + j];
            *(float4*)&xinS[ry * XS + cb] = *(float4*)xs;
        } else {                   // cols 64..127 = gate; same cols as vW in acc
#pragma unroll
            for (int j = 0; j < 4; j++) xg[j] = acc4[j] + sc1b2[cb + j];
        }
    }

    // ---- mix2 partials: p[d][o] = sum_c gate[c]*vW[d][c]*mixW2[c][o] --------
    if (w >= 2) {
        float p0 = 0, p1 = 0, p2 = 0, p3 = 0, p4 = 0, p5 = 0;
#pragma unroll
        for (int c = 0; c < 4; c++) {
            float2 m = *(const float2*)(mixW2 + (size_t)(cb - 64 + c) * 2);
            const float v0 = xg[c] * acc[0][c];
            const float v1 = xg[c] * acc[1][c];
            const float v2 = xg[c] * acc[2][c];
            p0 += v0 * m.x; p1 += v0 * m.y;
            p2 += v1 * m.x; p3 += v1 * m.y;
            p4 += v2 * m.x; p5 += v2 * m.y;
        }
        RED8(p0); RED8(p1); RED8(p2); RED8(p3); RED8(p4); RED8(p5);
        if (cx == 0) {
            pwp[ry][w - 2][0] = p0; pwp[ry][w - 2][1] = p1;
            pwp[ry][w - 2][2] = p2; pwp[ry][w - 2][3] = p3;
            pwp[ry][w - 2][4] = p4; pwp[ry][w - 2][5] = p5;
        }
    }
    __syncthreads();

    // ---- sc2 MLP: per node, 64-lane wave ------------------------------------
    {
        const float bb1 = sc2b1[ln];
        const float wn  = sc2W1[64 * 64 + ln];
        const float wq0 = sc2W2[ln * 2 + 0], wq1 = sc2W2[ln * 2 + 1];
#pragma unroll
        for (int r = 0; r < 2; r++) {
            const int nl = r * 4 + w;
            const float q00 = pwp[nl][0][0] + pwp[nl][1][0];
            const float q01 = pwp[nl][0][1] + pwp[nl][1][1];
            const float q10 = pwp[nl][0][2] + pwp[nl][1][2];
            const float q11 = pwp[nl][0][3] + pwp[nl][1][3];
            const float q20 = pwp[nl][0][4] + pwp[nl][1][4];
            const float q21 = pwp[nl][0][5] + pwp[nl][1][5];
            const float vn2 = sqrtf(q00 * q00 + q10 * q10 + q20 * q20);
            const float s1 = silu_f(xinS[nl * XS + ln]);
            s1s[w][ln] = s1;
            __builtin_amdgcn_s_waitcnt(0);
            float acc5 = bb1 + vn2 * wn;
#pragma unroll 8
            for (int i2 = 0; i2 < 64; i2++) acc5 += s1s[w][i2] * sc2W1[i2 * 64 + ln];
            const float h2 = silu_f(acc5);
            float q0 = h2 * wq0, q1 = h2 * wq1;
            RED64(q0); RED64(q1);
            if (ln == 0) {
                const int n = node0 + nl;
                const float gate = q1 + sc2b2[1];
                l0v[n] = q0 + sc2b2[0];
                l1v[(size_t)n * 3 + 0] = gate * q01;
                l1v[(size_t)n * 3 + 1] = gate * q11;
                l1v[(size_t)n * 3 + 2] = gate * q21;
            }
        }
    }
}

// ---------- pairpre v2: 384 blocks (32 j x 8 h-groups), coalesced stores ----
__global__ __launch_bounds__(256)
void pairpre_k(const float* __restrict__ l1v, const float* __restrict__ pos,
               const float* __restrict__ l0v,
               const float* __restrict__ vvW1, const float* __restrict__ vrW1,
               const float* __restrict__ sW1, const float* __restrict__ sb1,
               float* __restrict__ Pv, float* __restrict__ Pr,
               float* __restrict__ Ps) {
    const int jl = threadIdx.x & 31;
    const int hq = threadIdx.x >> 5;        // 0..7
    const int j  = blockIdx.x * 32 + jl;
    const float lj0 = l1v[j * 3 + 0], lj1 = l1v[j * 3 + 1], lj2 = l1v[j * 3 + 2];
    const float pj0 = pos[j * 3 + 0], pj1 = pos[j * 3 + 1], pj2 = pos[j * 3 + 2];
    const float l0j = l0v[j];
#pragma unroll
    for (int hh = 0; hh < 4; hh++) {
        const int h = hq * 4 + hh;
        if (h < 30) {
#pragma unroll
            for (int a = 0; a < 3; a++) {
                float v = lj0 * vvW1[(3 * a + 0) * 30 + h] + lj1 * vvW1[(3 * a + 1) * 30 + h]
                        + lj2 * vvW1[(3 * a + 2) * 30 + h];
                float r = pj0 * vrW1[(3 * a + 0) * 30 + h] + pj1 * vrW1[(3 * a + 1) * 30 + h]
                        + pj2 * vrW1[(3 * a + 2) * 30 + h];
                Pv[(size_t)(a * 30 + h) * NNODES + j] = v;
                Pr[(size_t)(a * 30 + h) * NNODES + j] = r;
            }
            Ps[(size_t)h * NNODES + j] = sb1[h] + l0j * sW1[30 + h];
        }
    }
}

// ---------- pair kernel v3: 2 i-atoms per thread, packed f32 (v_pk_fma) -----
// Grid (A/4, B), 192 threads: t -> g=t/96 (i-pair), j=t%96; i = bx*4+2g+{0,1}.
__global__ __launch_bounds__(192)
void pair_k(const float* __restrict__ l0v, const float* __restrict__ l1v,
            const float* __restrict__ Pv, const float* __restrict__ Pr,
            const float* __restrict__ Ps,
            const float* __restrict__ vvb1, const float* __restrict__ vrb1,
            const float* __restrict__ sW1,
            const float* __restrict__ vvW2, const float* __restrict__ vrW2,
            const float* __restrict__ sW2,
            const float* __restrict__ vvb2, const float* __restrict__ vrb2,
            const float* __restrict__ sb2,
            const float* __restrict__ hW1,  const float* __restrict__ hb1,
            const float* __restrict__ hW2,  const float* __restrict__ hb2,
            float* __restrict__ out) {
    const int t = threadIdx.x;
    const int b = blockIdx.y;
    const int g = (t >= 96) ? 1 : 0;
    const int j = t - g * 96;
    const int i0 = blockIdx.x * 4 + g * 2;
    const int ni0 = b * A_ATOMS + i0;
    const int ni1 = ni0 + 1;
    const int nj  = b * A_ATOMS + j;

    const v2f li0 = { l1v[ni0 * 3 + 0], l1v[ni1 * 3 + 0] };
    const v2f li1 = { l1v[ni0 * 3 + 1], l1v[ni1 * 3 + 1] };
    const v2f li2 = { l1v[ni0 * 3 + 2], l1v[ni1 * 3 + 2] };
    const v2f s0i = { l0v[ni0], l0v[ni1] };

    v2f t9[9];
#pragma unroll
    for (int l = 0; l < 9; l++) t9[l] = (v2f)(vvb2[l] + vrb2[l] + sb2[l]);

    for (int h = 0; h < 30; h++) {
        const float pv0 = Pv[(size_t)h * NNODES + nj];
        const float pv1 = Pv[(size_t)(30 + h) * NNODES + nj];
        const float pv2 = Pv[(size_t)(60 + h) * NNODES + nj];
        const float pr0 = Pr[(size_t)h * NNODES + nj];
        const float pr1 = Pr[(size_t)(30 + h) * NNODES + nj];
        const float pr2 = Pr[(size_t)(60 + h) * NNODES + nj];
        const float ps  = Ps[(size_t)h * NNODES + nj];

        v2f av = (v2f)(vvb1[h]) + li0 * pv0 + li1 * pv1 + li2 * pv2;
        v2f ar = (v2f)(vrb1[h]) + li0 * pr0 + li1 * pr1 + li2 * pr2;
        v2f as = (v2f)(ps) + s0i * sW1[h];
        av = silu2(av); ar = silu2(ar); as = silu2(as);
#pragma unroll
        for (int l = 0; l < 9; l++)
            t9[l] += av * vvW2[h * 9 + l] + ar * vrW2[h * 9 + l] + as * sW2[h * 9 + l];
    }

    v2f o9[9];
#pragma unroll
    for (int l = 0; l < 9; l++) o9[l] = (v2f)(hb2[l]);
    for (int h = 0; h < 30; h++) {
        v2f a = (v2f)(hb1[h]);
#pragma unroll
        for (int m = 0; m < 9; m++) a += t9[m] * hW1[m * 30 + h];
        a = silu2(a);
#pragma unroll
        for (int l = 0; l < 9; l++) o9[l] += a * hW2[h * 9 + l];
    }

    // out[((b*A+i)*3+k)*288 + j*3 + l]
    const size_t rb0 = (size_t)ni0;
#pragma unroll
    for (int k = 0; k < 3; k++) {
        const size_t off0 = (rb0 * 3 + k) * 288 + (size_t)j * 3;
        const size_t off1 = off0 + 3 * 288;
        out[off0 + 0] = o9[3 * k + 0].x;
        out[off0 + 1] = o9[3 * k + 1].x;
        out[off0 + 2] = o9[3 * k + 2].x;
        out[off1 + 0] = o9[3 * k + 0].y;
        out[off1 + 1] = o9[3 * k + 1].y;
        out[off1 + 2] = o9[3 * k + 2].y;
    }
}

extern "C" void kernel_launch(void* const* d_in, const int* in_sizes, int n_in,
                              void* d_out, int out_size, void* d_ws, size_t ws_size,
                              hipStream_t stream) {
    const float* pos   = (const float*)d_in[0];
    const float* srep  = (const float*)d_in[1];
    const float* vrep  = (const float*)d_in[2];
    const float* mixW1 = (const float*)d_in[3];
    const float* sc1W1 = (const float*)d_in[4];
    const float* sc1b1 = (const float*)d_in[5];
    const float* sc1W2 = (const float*)d_in[6];
    const float* sc1b2 = (const float*)d_in[7];
    const float* mixW2 = (const float*)d_in[8];
    const float* sc2W1 = (const float*)d_in[9];
    const float* sc2b1 = (const float*)d_in[10];
    const float* sc2W2 = (const float*)d_in[11];
    const float* sc2b2 = (const float*)d_in[12];
    const float* vvW1  = (const float*)d_in[13];
    const float* vvb1  = (const float*)d_in[14];
    const float* vvW2  = (const float*)d_in[15];
    const float* vvb2  = (const float*)d_in[16];
    const float* vrW1  = (const float*)d_in[17];
    const float* vrb1  = (const float*)d_in[18];
    const float* vrW2  = (const float*)d_in[19];
    const float* vrb2  = (const float*)d_in[20];
    const float* sW1   = (const float*)d_in[21];
    const float* sb1   = (const float*)d_in[22];
    const float* sW2   = (const float*)d_in[23];
    const float* sb2   = (const float*)d_in[24];
    const float* hW1   = (const float*)d_in[25];
    const float* hb1   = (const float*)d_in[26];
    const float* hW2   = (const float*)d_in[27];
    const float* hb2   = (const float*)d_in[28];

    float* ws  = (float*)d_ws;
    float* Pv  = ws;                    // 90*12288 = 1,105,920
    float* Pr  = Pv + 1105920;          // 1,105,920
    float* Ps  = Pr + 1105920;          // 30*12288 = 368,640
    float* l0v = Ps + 368640;           // 12,288
    float* l1v = l0v + 12288;           // 36,864
    float* outf = (float*)d_out;

    // 1. fused node stage -> l0, l1
    node_k<<<NNODES / NB, 256, 0, stream>>>(
        vrep, mixW1, srep,
        sc1W1, sc1b1, sc1W2, sc1b2,
        mixW2, sc2W1, sc2b1, sc2W2, sc2b2,
        l0v, l1v);

    // 2. P-tables (coalesced j-major stores, 384 blocks)
    pairpre_k<<<NNODES / 32, 256, 0, stream>>>(l1v, pos, l0v, vvW1, vrW1,
                                               sW1, sb1, Pv, Pr, Ps);

    // 3. pair stage (2 i per thread, packed f32)
    pair_k<<<dim3(A_ATOMS / 4, BATCH), 192, 0, stream>>>(
        l0v, l1v, Pv, Pr, Ps,
        vvb1, vrb1, sW1,
        vvW2, vrW2, sW2,
        vvb2, vrb2, sb2,
        hW1, hb1, hW2, hb2,
        outf);
}

// Round 2
// 261.006 us; speedup vs baseline: 1.1350x; 1.1214x over previous
//
#include <hip/hip_runtime.h>
#include <cstddef>

#define A_ATOMS 96
#define BATCH   128
#define NNODES  12288   // B*A
#define NB      8       // nodes per block (node_k)
#define AS      132     // AsL / workS stride (132%32=4)
#define XS      196     // xinS stride (196%32=4)

typedef float v2f __attribute__((ext_vector_type(2)));

__device__ __forceinline__ float silu_f(float x) {
    float e = __expf(-x);
    return x * __builtin_amdgcn_rcpf(1.0f + e);
}
__device__ __forceinline__ v2f silu2(v2f x) {
    v2f r; r.x = silu_f(x.x); r.y = silu_f(x.y); return r;
}

#define RED64(v) { v += __shfl_xor(v, 1); v += __shfl_xor(v, 2); v += __shfl_xor(v, 4); \
                   v += __shfl_xor(v, 8); v += __shfl_xor(v, 16); v += __shfl_xor(v, 32); }
#define RED16(v) { v += __shfl_xor(v, 1); v += __shfl_xor(v, 2); v += __shfl_xor(v, 4); \
                   v += __shfl_xor(v, 8); }

// ===== fused node kernel v4: 128 threads, 2 nodes/thread =====================
// Wave w (0..1) owns col-half [64w, 64w+64). Lane: cx = ln&15 (col quad),
// ry = ln>>4 (0..3); thread computes nodes {ry, ry+4} x cols [cb, cb+4).
// Per kc-step/wave: 8 weight loads + 12 LDS b128 + 192 FMA (384 issue cyc)
// -> own FMA stream covers ~300cyc L2 weight latency (was 96 FMA = exposed).
__global__ __launch_bounds__(128, 3)
void node_k(const float* __restrict__ vrep, const float* __restrict__ mixW1,
            const float* __restrict__ srep,
            const float* __restrict__ sc1W1, const float* __restrict__ sc1b1,
            const float* __restrict__ sc1W2, const float* __restrict__ sc1b2,
            const float* __restrict__ mixW2,
            const float* __restrict__ sc2W1, const float* __restrict__ sc2b1,
            const float* __restrict__ sc2W2, const float* __restrict__ sc2b2,
            float* __restrict__ l0v, float* __restrict__ l1v) {
    __shared__ float AsL[24 * AS];
    __shared__ float xinS[NB * XS];
    __shared__ float s1s[2][4][64];
    __shared__ float pwp[NB][6];     // mix2 results per node (single producer wave)

    const int t  = threadIdx.x;
    const int w  = t >> 6;           // wave: col half
    const int ln = t & 63;
    const int cx = ln & 15;          // col quad in half
    const int ry = ln >> 4;          // 0..3 -> nodes ry, ry+4
    const int cb = w * 64 + cx * 4;  // output col base 0..124
    const int row0  = blockIdx.x * 24;
    const int node0 = blockIdx.x * NB;

    // ---- stage vrep (24x128) and srep (8x128) into LDS ----------------------
#pragma unroll
    for (int it = 0; it < 6; it++) {
        const int idx = it * 128 + t;
        const int r   = idx >> 5;
        const int c4  = (idx & 31) * 4;
        *(float4*)&AsL[r * AS + c4] = *(const float4*)(vrep + (size_t)(row0 + r) * 128 + c4);
    }
#pragma unroll
    for (int it = 0; it < 2; it++) {
        const int idx = it * 128 + t;
        const int a   = idx >> 5;
        const int c4  = (idx & 31) * 4;
        *(float4*)&xinS[a * XS + c4] = *(const float4*)(srep + (size_t)(node0 + a) * 128 + c4);
    }
    __syncthreads();

    // ---- mix1: vmix[2 nodes][3 dims][4 cols] --------------------------------
    float acc[2][3][4];
#pragma unroll
    for (int p = 0; p < 2; p++)
#pragma unroll
        for (int d = 0; d < 3; d++)
#pragma unroll
            for (int j = 0; j < 4; j++) acc[p][d][j] = 0.0f;

    for (int kc = 0; kc < 128; kc += 8) {
        float a[2][3][8];
#pragma unroll
        for (int p = 0; p < 2; p++)
#pragma unroll
            for (int d = 0; d < 3; d++) {
                const int row = (3 * (ry + 4 * p) + d) * AS + kc;
                *(float4*)&a[p][d][0] = *(const float4*)&AsL[row];
                *(float4*)&a[p][d][4] = *(const float4*)&AsL[row + 4];
            }
#pragma unroll
        for (int kk = 0; kk < 8; kk++) {
            float b[4];
            *(float4*)b = *(const float4*)(mixW1 + (size_t)(kc + kk) * 128 + cb);
#pragma unroll
            for (int p = 0; p < 2; p++)
#pragma unroll
                for (int d = 0; d < 3; d++)
#pragma unroll
                    for (int j = 0; j < 4; j++)
                        acc[p][d][j] += a[p][d][kk] * b[j];
        }
    }
    // norms of vV (cols 0..63 -> wave 0); both nodes live in this thread
    if (w == 0) {
#pragma unroll
        for (int p = 0; p < 2; p++) {
            float nrm[4];
#pragma unroll
            for (int c = 0; c < 4; c++)
                nrm[c] = sqrtf(acc[p][0][c] * acc[p][0][c] + acc[p][1][c] * acc[p][1][c]
                             + acc[p][2][c] * acc[p][2][c]);
            *(float4*)&xinS[(ry + 4 * p) * XS + 128 + cb] = *(float4*)nrm;
        }
    }
    __syncthreads();

    // ---- sc1 layer 1: xin(192) @ sc1W1(192x128) -> silu ---------------------
    float* workS = AsL;
    {
        float acc3[2][4];
#pragma unroll
        for (int p = 0; p < 2; p++)
#pragma unroll
            for (int j = 0; j < 4; j++) acc3[p][j] = 0.0f;
        for (int kc = 0; kc < 192; kc += 8) {
            float af[2][8];
#pragma unroll
            for (int p = 0; p < 2; p++) {
                const int row = (ry + 4 * p) * XS + kc;
                *(float4*)&af[p][0] = *(const float4*)&xinS[row];
                *(float4*)&af[p][4] = *(const float4*)&xinS[row + 4];
            }
#pragma unroll
            for (int kk = 0; kk < 8; kk++) {
                float b[4];
                *(float4*)b = *(const float4*)(sc1W1 + (size_t)(kc + kk) * 128 + cb);
#pragma unroll
                for (int p = 0; p < 2; p++)
#pragma unroll
                    for (int j = 0; j < 4; j++) acc3[p][j] += af[p][kk] * b[j];
            }
        }
        // AsL reads all finished before the post-norm barrier -> safe to write
#pragma unroll
        for (int p = 0; p < 2; p++) {
            float h[4];
#pragma unroll
            for (int j = 0; j < 4; j++) h[j] = silu_f(acc3[p][j] + sc1b1[cb + j]);
            *(float4*)&workS[(ry + 4 * p) * AS + cb] = *(float4*)h;
        }
    }
    __syncthreads();

    // ---- sc1 layer 2: h(128) @ sc1W2(128x128) -------------------------------
    float xg[2][4];
    {
        float acc4[2][4];
#pragma unroll
        for (int p = 0; p < 2; p++)
#pragma unroll
            for (int j = 0; j < 4; j++) acc4[p][j] = 0.0f;
        for (int kc = 0; kc < 128; kc += 8) {
            float af[2][8];
#pragma unroll
            for (int p = 0; p < 2; p++) {
                const int row = (ry + 4 * p) * AS + kc;
                *(float4*)&af[p][0] = *(const float4*)&workS[row];
                *(float4*)&af[p][4] = *(const float4*)&workS[row + 4];
            }
#pragma unroll
            for (int kk = 0; kk < 8; kk++) {
                float b[4];
                *(float4*)b = *(const float4*)(sc1W2 + (size_t)(kc + kk) * 128 + cb);
#pragma unroll
                for (int p = 0; p < 2; p++)
#pragma unroll
                    for (int j = 0; j < 4; j++) acc4[p][j] += af[p][kk] * b[j];
            }
        }
        if (w == 0) {              // cols 0..63 = s_out -> xinS (raw; silu in sc2)
#pragma unroll
            for (int p = 0; p < 2; p++) {
                float xs[4];
#pragma unroll
                for (int j = 0; j < 4; j++) xs[j] = acc4[p][j] + sc1b2[cb + j];
                *(float4*)&xinS[(ry + 4 * p) * XS + cb] = *(float4*)xs;
            }
        } else {                   // cols 64..127 = gate; same cols as vW in acc
#pragma unroll
            for (int p = 0; p < 2; p++)
#pragma unroll
                for (int j = 0; j < 4; j++) xg[p][j] = acc4[p][j] + sc1b2[cb + j];
        }
    }

    // ---- mix2: p[d][o] = sum_c gate[c]*vW[d][c]*mixW2[c][o] (wave 1 only) ---
    if (w == 1) {
#pragma unroll
        for (int p = 0; p < 2; p++) {
            float p0 = 0, p1 = 0, p2 = 0, p3 = 0, p4 = 0, p5 = 0;
#pragma unroll
            for (int c = 0; c < 4; c++) {
                float2 m = *(const float2*)(mixW2 + (size_t)(cb - 64 + c) * 2);
                const float v0 = xg[p][c] * acc[p][0][c];
                const float v1 = xg[p][c] * acc[p][1][c];
                const float v2 = xg[p][c] * acc[p][2][c];
                p0 += v0 * m.x; p1 += v0 * m.y;
                p2 += v1 * m.x; p3 += v1 * m.y;
                p4 += v2 * m.x; p5 += v2 * m.y;
            }
            RED16(p0); RED16(p1); RED16(p2); RED16(p3); RED16(p4); RED16(p5);
            if (cx == 0) {
                const int nl = ry + 4 * p;
                pwp[nl][0] = p0; pwp[nl][1] = p1;
                pwp[nl][2] = p2; pwp[nl][3] = p3;
                pwp[nl][4] = p4; pwp[nl][5] = p5;
            }
        }
    }
    __syncthreads();

    // ---- sc2 MLP: each wave handles 4 nodes in one shared 64-dot ------------
    {
        const float bb1 = sc2b1[ln];
        const float wn  = sc2W1[64 * 64 + ln];
        const float wq0 = sc2W2[ln * 2 + 0], wq1 = sc2W2[ln * 2 + 1];
        float vn2[4], g0[4], g1[4], g2[4];
#pragma unroll
        for (int r = 0; r < 4; r++) {
            const int nl = r * 2 + w;
            const float q00 = pwp[nl][0], q10 = pwp[nl][2], q20 = pwp[nl][4];
            vn2[r] = sqrtf(q00 * q00 + q10 * q10 + q20 * q20);
            g0[r] = pwp[nl][1]; g1[r] = pwp[nl][3]; g2[r] = pwp[nl][5];
            s1s[w][r][ln] = silu_f(xinS[nl * XS + ln]);
        }
        __builtin_amdgcn_s_waitcnt(0);
        float acc5[4];
#pragma unroll
        for (int r = 0; r < 4; r++) acc5[r] = bb1 + vn2[r] * wn;
#pragma unroll 8
        for (int i2 = 0; i2 < 64; i2++) {
            const float wv = sc2W1[i2 * 64 + ln];
#pragma unroll
            for (int r = 0; r < 4; r++) acc5[r] += s1s[w][r][i2] * wv;
        }
#pragma unroll
        for (int r = 0; r < 4; r++) {
            const float h2 = silu_f(acc5[r]);
            float q0 = h2 * wq0, q1 = h2 * wq1;
            RED64(q0); RED64(q1);
            if (ln == 0) {
                const int n = node0 + r * 2 + w;
                const float gate = q1 + sc2b2[1];
                l0v[n] = q0 + sc2b2[0];
                l1v[(size_t)n * 3 + 0] = gate * g0[r];
                l1v[(size_t)n * 3 + 1] = gate * g1[r];
                l1v[(size_t)n * 3 + 2] = gate * g2[r];
            }
        }
    }
}

// ---------- pairpre v2: 384 blocks (32 j x 8 h-groups), coalesced stores ----
__global__ __launch_bounds__(256)
void pairpre_k(const float* __restrict__ l1v, const float* __restrict__ pos,
               const float* __restrict__ l0v,
               const float* __restrict__ vvW1, const float* __restrict__ vrW1,
               const float* __restrict__ sW1, const float* __restrict__ sb1,
               float* __restrict__ Pv, float* __restrict__ Pr,
               float* __restrict__ Ps) {
    const int jl = threadIdx.x & 31;
    const int hq = threadIdx.x >> 5;        // 0..7
    const int j  = blockIdx.x * 32 + jl;
    const float lj0 = l1v[j * 3 + 0], lj1 = l1v[j * 3 + 1], lj2 = l1v[j * 3 + 2];
    const float pj0 = pos[j * 3 + 0], pj1 = pos[j * 3 + 1], pj2 = pos[j * 3 + 2];
    const float l0j = l0v[j];
#pragma unroll
    for (int hh = 0; hh < 4; hh++) {
        const int h = hq * 4 + hh;
        if (h < 30) {
#pragma unroll
            for (int a = 0; a < 3; a++) {
                float v = lj0 * vvW1[(3 * a + 0) * 30 + h] + lj1 * vvW1[(3 * a + 1) * 30 + h]
                        + lj2 * vvW1[(3 * a + 2) * 30 + h];
                float r = pj0 * vrW1[(3 * a + 0) * 30 + h] + pj1 * vrW1[(3 * a + 1) * 30 + h]
                        + pj2 * vrW1[(3 * a + 2) * 30 + h];
                Pv[(size_t)(a * 30 + h) * NNODES + j] = v;
                Pr[(size_t)(a * 30 + h) * NNODES + j] = r;
            }
            Ps[(size_t)h * NNODES + j] = sb1[h] + l0j * sW1[30 + h];
        }
    }
}

// ---------- pair kernel v3: 2 i-atoms per thread, packed f32 (v_pk_fma) -----
// Grid (A/4, B), 192 threads: t -> g=t/96 (i-pair), j=t%96; i = bx*4+2g+{0,1}.
__global__ __launch_bounds__(192)
void pair_k(const float* __restrict__ l0v, const float* __restrict__ l1v,
            const float* __restrict__ Pv, const float* __restrict__ Pr,
            const float* __restrict__ Ps,
            const float* __restrict__ vvb1, const float* __restrict__ vrb1,
            const float* __restrict__ sW1,
            const float* __restrict__ vvW2, const float* __restrict__ vrW2,
            const float* __restrict__ sW2,
            const float* __restrict__ vvb2, const float* __restrict__ vrb2,
            const float* __restrict__ sb2,
            const float* __restrict__ hW1,  const float* __restrict__ hb1,
            const float* __restrict__ hW2,  const float* __restrict__ hb2,
            float* __restrict__ out) {
    const int t = threadIdx.x;
    const int b = blockIdx.y;
    const int g = (t >= 96) ? 1 : 0;
    const int j = t - g * 96;
    const int i0 = blockIdx.x * 4 + g * 2;
    const int ni0 = b * A_ATOMS + i0;
    const int ni1 = ni0 + 1;
    const int nj  = b * A_ATOMS + j;

    const v2f li0 = { l1v[ni0 * 3 + 0], l1v[ni1 * 3 + 0] };
    const v2f li1 = { l1v[ni0 * 3 + 1], l1v[ni1 * 3 + 1] };
    const v2f li2 = { l1v[ni0 * 3 + 2], l1v[ni1 * 3 + 2] };
    const v2f s0i = { l0v[ni0], l0v[ni1] };

    v2f t9[9];
#pragma unroll
    for (int l = 0; l < 9; l++) t9[l] = (v2f)(vvb2[l] + vrb2[l] + sb2[l]);

    for (int h = 0; h < 30; h++) {
        const float pv0 = Pv[(size_t)h * NNODES + nj];
        const float pv1 = Pv[(size_t)(30 + h) * NNODES + nj];
        const float pv2 = Pv[(size_t)(60 + h) * NNODES + nj];
        const float pr0 = Pr[(size_t)h * NNODES + nj];
        const float pr1 = Pr[(size_t)(30 + h) * NNODES + nj];
        const float pr2 = Pr[(size_t)(60 + h) * NNODES + nj];
        const float ps  = Ps[(size_t)h * NNODES + nj];

        v2f av = (v2f)(vvb1[h]) + li0 * pv0 + li1 * pv1 + li2 * pv2;
        v2f ar = (v2f)(vrb1[h]) + li0 * pr0 + li1 * pr1 + li2 * pr2;
        v2f as = (v2f)(ps) + s0i * sW1[h];
        av = silu2(av); ar = silu2(ar); as = silu2(as);
#pragma unroll
        for (int l = 0; l < 9; l++)
            t9[l] += av * vvW2[h * 9 + l] + ar * vrW2[h * 9 + l] + as * sW2[h * 9 + l];
    }

    v2f o9[9];
#pragma unroll
    for (int l = 0; l < 9; l++) o9[l] = (v2f)(hb2[l]);
    for (int h = 0; h < 30; h++) {
        v2f a = (v2f)(hb1[h]);
#pragma unroll
        for (int m = 0; m < 9; m++) a += t9[m] * hW1[m * 30 + h];
        a = silu2(a);
#pragma unroll
        for (int l = 0; l < 9; l++) o9[l] += a * hW2[h * 9 + l];
    }

    // out[((b*A+i)*3+k)*288 + j*3 + l]
    const size_t rb0 = (size_t)ni0;
#pragma unroll
    for (int k = 0; k < 3; k++) {
        const size_t off0 = (rb0 * 3 + k) * 288 + (size_t)j * 3;
        const size_t off1 = off0 + 3 * 288;
        out[off0 + 0] = o9[3 * k + 0].x;
        out[off0 + 1] = o9[3 * k + 1].x;
        out[off0 + 2] = o9[3 * k + 2].x;
        out[off1 + 0] = o9[3 * k + 0].y;
        out[off1 + 1] = o9[3 * k + 1].y;
        out[off1 + 2] = o9[3 * k + 2].y;
    }
}

extern "C" void kernel_launch(void* const* d_in, const int* in_sizes, int n_in,
                              void* d_out, int out_size, void* d_ws, size_t ws_size,
                              hipStream_t stream) {
    const float* pos   = (const float*)d_in[0];
    const float* srep  = (const float*)d_in[1];
    const float* vrep  = (const float*)d_in[2];
    const float* mixW1 = (const float*)d_in[3];
    const float* sc1W1 = (const float*)d_in[4];
    const float* sc1b1 = (const float*)d_in[5];
    const float* sc1W2 = (const float*)d_in[6];
    const float* sc1b2 = (const float*)d_in[7];
    const float* mixW2 = (const float*)d_in[8];
    const float* sc2W1 = (const float*)d_in[9];
    const float* sc2b1 = (const float*)d_in[10];
    const float* sc2W2 = (const float*)d_in[11];
    const float* sc2b2 = (const float*)d_in[12];
    const float* vvW1  = (const float*)d_in[13];
    const float* vvb1  = (const float*)d_in[14];
    const float* vvW2  = (const float*)d_in[15];
    const float* vvb2  = (const float*)d_in[16];
    const float* vrW1  = (const float*)d_in[17];
    const float* vrb1  = (const float*)d_in[18];
    const float* vrW2  = (const float*)d_in[19];
    const float* vrb2  = (const float*)d_in[20];
    const float* sW1   = (const float*)d_in[21];
    const float* sb1   = (const float*)d_in[22];
    const float* sW2   = (const float*)d_in[23];
    const float* sb2   = (const float*)d_in[24];
    const float* hW1   = (const float*)d_in[25];
    const float* hb1   = (const float*)d_in[26];
    const float* hW2   = (const float*)d_in[27];
    const float* hb2   = (const float*)d_in[28];

    float* ws  = (float*)d_ws;
    float* Pv  = ws;                    // 90*12288 = 1,105,920
    float* Pr  = Pv + 1105920;          // 1,105,920
    float* Ps  = Pr + 1105920;          // 30*12288 = 368,640
    float* l0v = Ps + 368640;           // 12,288
    float* l1v = l0v + 12288;           // 36,864
    float* outf = (float*)d_out;

    // 1. fused node stage -> l0, l1
    node_k<<<NNODES / NB, 128, 0, stream>>>(
        vrep, mixW1, srep,
        sc1W1, sc1b1, sc1W2, sc1b2,
        mixW2, sc2W1, sc2b1, sc2W2, sc2b2,
        l0v, l1v);

    // 2. P-tables (coalesced j-major stores, 384 blocks)
    pairpre_k<<<NNODES / 32, 256, 0, stream>>>(l1v, pos, l0v, vvW1, vrW1,
                                               sW1, sb1, Pv, Pr, Ps);

    // 3. pair stage (2 i per thread, packed f32)
    pair_k<<<dim3(A_ATOMS / 4, BATCH), 192, 0, stream>>>(
        l0v, l1v, Pv, Pr, Ps,
        vvb1, vrb1, sW1,
        vvW2, vrW2, sW2,
        vvb2, vrb2, sb2,
        hW1, hb1, hW2, hb2,
        outf);
}